// Round 11
// baseline (987.784 us; speedup 1.0000x reference)
//
#include <hip/hip_runtime.h>
#include <stdint.h>

typedef unsigned short u16;
typedef __attribute__((ext_vector_type(8))) short bf16x8;
typedef __attribute__((ext_vector_type(4))) float f32x4;

#define HD 256
#define AST 264       // A_lds row stride in u16 (528 B: 16B-aligned, bank-rotating)
#define GRP 64        // nodes per block-iteration in k_bp
#define CORR_CAP 2048 // backtracking-pair capacity (expected ~16 for this graph)

static __device__ __forceinline__ float b2f(u16 x){
  union{float f; unsigned u;} v; v.u = ((unsigned)x)<<16; return v.f;
}
static __device__ __forceinline__ u16 f2b(float f){
  union{float f; unsigned u;} v; v.f = f;
  unsigned r = v.u + 0x7fffu + ((v.u>>16)&1u);
  return (u16)(r>>16);
}
// accumulate relu(I + V) (both bf16 pairs) into a[4]
static __device__ __forceinline__ void racc2(float* a, uint2 iv, uint2 vv){
  float t0 = b2f((u16)iv.x)       + b2f((u16)vv.x);
  float t1 = b2f((u16)(iv.x>>16)) + b2f((u16)(vv.x>>16));
  float t2 = b2f((u16)iv.y)       + b2f((u16)vv.y);
  float t3 = b2f((u16)(iv.y>>16)) + b2f((u16)(vv.y>>16));
  a[0] += t0>0.f?t0:0.f; a[1] += t1>0.f?t1:0.f;
  a[2] += t2>0.f?t2:0.f; a[3] += t3>0.f?t3:0.f;
}
static __device__ __forceinline__ void racc1(float* a, uint2 iv){
  float t0 = b2f((u16)iv.x), t1 = b2f((u16)(iv.x>>16));
  float t2 = b2f((u16)iv.y), t3 = b2f((u16)(iv.y>>16));
  a[0] += t0>0.f?t0:0.f; a[1] += t1>0.f?t1:0.f;
  a[2] += t2>0.f?t2:0.f; a[3] += t3>0.f?t3:0.f;
}

// ---------------- fused prep: 4 B-tables + xnf + zero(deg2 incl npairs) ----------------
static __device__ __forceinline__ void prep_frag_body(const float* __restrict__ W,
    int k0, int kmax, u16* __restrict__ out, int lb, int tid){
  int g = lb*256 + tid;
  int i = g & 7, l = (g>>3)&63, t = g>>9;
  int nj = t & 15, ks = t >> 4;
  int n = nj*16 + (l&15);
  int k = ks*32 + (l>>4)*8 + i;
  float v = (k < kmax) ? W[(size_t)(k0+k)*HD + n] : 0.f;
  out[g] = f2b(v);
}
__global__ void k_prep_all(const float* __restrict__ Wi, const float* __restrict__ Wh,
                           const float* __restrict__ Wo, const float* __restrict__ xn,
                           u16* __restrict__ BT_P, u16* __restrict__ BT_Wh,
                           u16* __restrict__ BT_Ra, u16* __restrict__ BT_Wob,
                           u16* __restrict__ xnf, int* __restrict__ deg2,
                           int N, int zb){
  int b = blockIdx.x, tid = threadIdx.x;
  if (b < 64){ prep_frag_body(Wi, 0, 35, BT_P, b, tid); return; }
  b -= 64;
  if (b < 256){ prep_frag_body(Wh, 0, 256, BT_Wh, b, tid); return; }
  b -= 256;
  if (b < 64){ prep_frag_body(Wo, 0, 35, BT_Ra, b, tid); return; }
  b -= 64;
  if (b < 256){ prep_frag_body(Wo, 35, 256, BT_Wob, b, tid); return; }
  b -= 256;
  if (b < zb){
    int i = b*256 + tid;
    if (i < 2*N+1) deg2[i] = 0;
    return;
  }
  b -= zb;
  { // xnf
    long long g = (long long)b*256 + tid;
    int v2 = (int)(g >> 6), c = (int)(g & 63);
    if (v2 >= N) return;
    float v = (c < 35) ? xn[(size_t)v2*35 + c] : 0.f;
    xnf[g] = f2b(v);
  }
}

// ---------------- fused histograms: tgt -> deg2[0..N), dst -> deg2[N..2N) ----------------
__global__ void k_hist2(const int* __restrict__ tgt, const int* __restrict__ edst,
                        int* __restrict__ deg2, int K, int E, int N, int kgrid){
  int b = blockIdx.x;
  if (b < kgrid){
    int i = b*256 + threadIdx.x;
    if (i < K) atomicAdd(&deg2[tgt[i]], 1);
  } else {
    int i = (b-kgrid)*256 + threadIdx.x;
    if (i < E) atomicAdd(&deg2[N + edst[i]], 1);
  }
}

// ---------------- 3-phase parallel exclusive scan ----------------
__global__ void k_scan_p1(const int* __restrict__ deg, int n, int* __restrict__ bsum){
  int i = blockIdx.x*256 + threadIdx.x;
  int v = (i < n) ? deg[i] : 0;
  #pragma unroll
  for (int o=32; o>0; o>>=1) v += __shfl_down(v, o);
  __shared__ int w[4];
  if ((threadIdx.x&63)==0) w[threadIdx.x>>6] = v;
  __syncthreads();
  if (threadIdx.x==0) bsum[blockIdx.x] = w[0]+w[1]+w[2]+w[3];
}
__global__ __launch_bounds__(1024) void k_scan_p2(int* __restrict__ bsum, int nb,
                                                  int* __restrict__ total_dst){
  __shared__ int sm[1024];
  int t = threadIdx.x;
  int v = (t < nb) ? bsum[t] : 0;
  sm[t] = v; __syncthreads();
  for (int o=1; o<1024; o<<=1){
    int u = (t>=o) ? sm[t-o] : 0;
    __syncthreads();
    sm[t] += u;
    __syncthreads();
  }
  if (t < nb) bsum[t] = sm[t] - v;
  if (t == 1023 && total_dst) *total_dst = sm[1023];
}
__global__ void k_scan_p3(const int* __restrict__ deg, const int* __restrict__ bsum, int n,
                          int* __restrict__ start, int* __restrict__ cursor){
  int t = threadIdx.x;
  int i = blockIdx.x*256 + t;
  int v = (i < n) ? deg[i] : 0;
  __shared__ int sm[256];
  sm[t] = v; __syncthreads();
  for (int o=1; o<256; o<<=1){
    int u = (t>=o) ? sm[t-o] : 0;
    __syncthreads();
    sm[t] += u;
    __syncthreads();
  }
  int ex = sm[t] - v + bsum[blockIdx.x];
  if (i < n){ start[i] = ex; cursor[i] = ex; }
}

// ---------------- fused fills: tgt buckets [0,K), dst buckets [K,K+E) ----------------
__global__ void k_fill2(const int* __restrict__ tgt, const int* __restrict__ teid,
                        const int* __restrict__ edst, int* __restrict__ cursor2,
                        int* __restrict__ bucket2, int K, int E, int N, int kgrid){
  int b = blockIdx.x;
  if (b < kgrid){
    int i = b*256 + threadIdx.x;
    if (i >= K) return;
    int pos = atomicAdd(&cursor2[tgt[i]], 1);
    bucket2[pos] = teid[i];
  } else {
    int e = (b-kgrid)*256 + threadIdx.x;
    if (e >= E) return;
    int pos = atomicAdd(&cursor2[N + edst[e]], 1);
    bucket2[pos] = e;   // original edge id; absolute pos in [K, K+E)
  }
}

// ---------------- permuted edge arrays + xep (new label = dst-sorted rank) ----------------
__global__ void k_perm_xep(const int* __restrict__ bucket2, int K,
                           const int* __restrict__ esrc, const int* __restrict__ edst,
                           const float* __restrict__ xe,
                           int* __restrict__ esrc_p, int* __restrict__ edst_p,
                           float* __restrict__ xep, int E){
  int e = blockIdx.x*256 + threadIdx.x;
  if (e >= E) return;
  int o = bucket2[K + e];
  esrc_p[e] = esrc[o];
  edst_p[e] = edst[o];
  #pragma unroll
  for (int k=0;k<5;k++) xep[(size_t)e*5+k] = xe[(size_t)o*5+k];
}

// ---------------- fused alpha gather + backtracking pair list ----------------
__global__ void k_alpha_pairs(const float* __restrict__ tree_m,
                              const int* __restrict__ start2, const int* __restrict__ bucket2,
                              u16* __restrict__ alpha16,
                              const int* __restrict__ esrc_p, const int* __restrict__ edst_p,
                              int* __restrict__ npairs, int2* __restrict__ pairs,
                              int N, int E, int K, int agrid){
  int b = blockIdx.x;
  if (b < agrid){
    int v = (int)(((long long)b*256 + threadIdx.x)>>6);
    int l = threadIdx.x & 63;
    if (v >= N) return;
    int s = start2[v], e2 = start2[v+1];     // absolute into bucket2 (tgt part)
    float a0=0.f,a1=0.f,a2=0.f,a3=0.f;
    for (int j=s;j<e2;j++){
      float4 tv = *(const float4*)(tree_m + (size_t)bucket2[j]*HD + l*4);
      a0 += tv.x; a1 += tv.y; a2 += tv.z; a3 += tv.w;
    }
    ushort4 o; o.x=f2b(a0); o.y=f2b(a1); o.z=f2b(a2); o.w=f2b(a3);
    *(ushort4*)(alpha16 + (size_t)v*HD + l*4) = o;
  } else {
    int e = (b-agrid)*256 + threadIdx.x;
    if (e >= E) return;
    int u = esrc_p[e], v = edst_p[e];
    int s = start2[N+u] - K, t = start2[N+u+1] - K;
    for (int ep=s; ep<t; ep++){
      if (esrc_p[ep] == v){
        int pos = atomicAdd(npairs, 1);
        if (pos < CORR_CAP) pairs[pos] = (int2){e, ep};
      }
    }
  }
}

// ---------------- fused P/R GEMM: P = xnf@Wi_a, R = xnf@Wo_a ----------------
__global__ __launch_bounds__(512, 4) void k_pr2(
    const u16* __restrict__ xnf, const u16* __restrict__ BT_P,
    const u16* __restrict__ BT_Ra, u16* __restrict__ P, u16* __restrict__ R, int M)
{
  const int tid = threadIdx.x;
  const int w = tid>>6, l = tid&63;
  const int lr = l&15, lq = l>>4;
  const int nrb = (M+15)>>4;
  bf16x8 BP0[2], BP1[2], BR0[2], BR1[2];
  #pragma unroll
  for (int ks=0; ks<2; ks++){
    BP0[ks] = *(const bf16x8*)(BT_P  + (size_t)((ks*16 + w*2  )*512) + l*8);
    BP1[ks] = *(const bf16x8*)(BT_P  + (size_t)((ks*16 + w*2+1)*512) + l*8);
    BR0[ks] = *(const bf16x8*)(BT_Ra + (size_t)((ks*16 + w*2  )*512) + l*8);
    BR1[ks] = *(const bf16x8*)(BT_Ra + (size_t)((ks*16 + w*2+1)*512) + l*8);
  }
  const int c0 = w*32 + lr, c1 = w*32 + 16 + lr;
  for (int rb = blockIdx.x; rb < nrb; rb += gridDim.x){
    int r = rb*16 + lr; int rc = min(r, M-1);
    const u16* fr = xnf + (size_t)rc*64 + lq*8;
    bf16x8 a0 = *(const bf16x8*)(fr);
    bf16x8 a1 = *(const bf16x8*)(fr + 32);
    f32x4 p0={0.f,0.f,0.f,0.f}, p1={0.f,0.f,0.f,0.f};
    f32x4 r0={0.f,0.f,0.f,0.f}, r1={0.f,0.f,0.f,0.f};
    p0 = __builtin_amdgcn_mfma_f32_16x16x32_bf16(a0, BP0[0], p0, 0,0,0);
    p0 = __builtin_amdgcn_mfma_f32_16x16x32_bf16(a1, BP0[1], p0, 0,0,0);
    p1 = __builtin_amdgcn_mfma_f32_16x16x32_bf16(a0, BP1[0], p1, 0,0,0);
    p1 = __builtin_amdgcn_mfma_f32_16x16x32_bf16(a1, BP1[1], p1, 0,0,0);
    r0 = __builtin_amdgcn_mfma_f32_16x16x32_bf16(a0, BR0[0], r0, 0,0,0);
    r0 = __builtin_amdgcn_mfma_f32_16x16x32_bf16(a1, BR0[1], r0, 0,0,0);
    r1 = __builtin_amdgcn_mfma_f32_16x16x32_bf16(a0, BR1[0], r1, 0,0,0);
    r1 = __builtin_amdgcn_mfma_f32_16x16x32_bf16(a1, BR1[1], r1, 0,0,0);
    #pragma unroll
    for (int reg=0; reg<4; reg++){
      int gm = rb*16 + lq*4 + reg;
      if (gm < M){
        P[(size_t)gm*HD + c0] = f2b(p0[reg]);
        P[(size_t)gm*HD + c1] = f2b(p1[reg]);
        R[(size_t)gm*HD + c0] = f2b(r0[reg]);
        R[(size_t)gm*HD + c1] = f2b(r1[reg]);
      }
    }
  }
}

// ---------------- I[e] = P[src[e]] + xe[e]@Wi[35:40]  (pre-relu, bf16) ----------------
__global__ __launch_bounds__(256, 8) void k_build_I(
    const u16* __restrict__ P, const float* __restrict__ xep,
    const int* __restrict__ esrc_p, const float* __restrict__ Wi,
    u16* __restrict__ I, int E)
{
  const int l = threadIdx.x & 63;
  const int wid = (blockIdx.x*256 + threadIdx.x) >> 6;
  const int nw = gridDim.x*4;
  float wq[5][4];
  #pragma unroll
  for (int k=0;k<5;k++){
    float4 t = *(const float4*)(Wi + (size_t)(35+k)*HD + l*4);
    wq[k][0]=t.x; wq[k][1]=t.y; wq[k][2]=t.z; wq[k][3]=t.w;
  }
  for (int e = wid; e < E; e += nw){
    int s = esrc_p[e];
    const float* xp = xep + (size_t)e*5;
    float x0=xp[0], x1=xp[1], x2=xp[2], x3=xp[3], x4=xp[4];
    uint2 uv = *(const uint2*)(P + (size_t)s*HD + l*4);
    float v[4] = { b2f((u16)uv.x), b2f((u16)(uv.x>>16)),
                   b2f((u16)uv.y), b2f((u16)(uv.y>>16)) };
    #pragma unroll
    for (int j=0;j<4;j++)
      v[j] += x0*wq[0][j] + x1*wq[1][j] + x2*wq[2][j] + x3*wq[3][j] + x4*wq[4][j];
    ushort4 o; o.x=f2b(v[0]); o.y=f2b(v[1]); o.z=f2b(v[2]); o.w=f2b(v[3]);
    *(ushort4*)(I + (size_t)e*HD + l*4) = o;
  }
}

// msgA[p] = relu(I[pairs[p].y])  (msg_0 of partner edges)
__global__ void k_msgA0(const u16* __restrict__ I, const int2* __restrict__ pairs,
                        const int* __restrict__ npairs_p, float* __restrict__ msgA){
  int np = *npairs_p; if (np > CORR_CAP) np = CORR_CAP;
  int t = threadIdx.x;
  for (int p = blockIdx.x; p < np; p += gridDim.x){
    int ep = pairs[p].y;
    float v = b2f(I[(size_t)ep*HD + t]);
    msgA[(size_t)p*HD + t] = v > 0.f ? v : 0.f;
  }
}

// ---------------- fused BP step: per node v ----------------
// S[v] = alpha[v] + sum_{in-edges e} relu(I[e] + Vprev[src[e]])   (Vprev NULL -> relu(I))
// start_d entries are absolute (+KBIAS); edge labels are (value - KBIAS).
// mode 0: Vout[v] = S[v]@BTf (bf16)      mode 1: hout = relu(Radd + S@BTf + bias); Sout written
// NOTE: launch_bounds min-waves MUST stay 4 — at 8 the 64 B-frag VGPRs spill to scratch
// (round-8 regression). LDS-staged output + unroll-4 gathers REGRESSED (round-10:
// FETCH/WRITE +75MB each, scratch signature) — this is the round-9 verified version.
__global__ __launch_bounds__(512, 4) void k_bp(
    const u16* __restrict__ I, const u16* __restrict__ Vprev,
    const u16* __restrict__ alpha16, const int* __restrict__ start_d, int KBIAS,
    const int* __restrict__ esrc_p, const u16* __restrict__ BTf,
    const u16* __restrict__ Radd, const float* __restrict__ bias,
    u16* __restrict__ Sout, u16* __restrict__ Vout, float* __restrict__ hout,
    int N, int mode)
{
  __shared__ u16 A_lds[GRP][AST];   // 33,792 B -> 4 blocks/CU (LDS-capped), 32 waves/CU
  const int tid = threadIdx.x;
  const int w = tid>>6, l = tid&63;
  const int lr = l&15, lq = l>>4;
  const int ngrp = (N+GRP-1)/GRP;

  bf16x8 B0[8], B1[8];
  #pragma unroll
  for (int ks=0; ks<8; ks++){
    B0[ks] = *(const bf16x8*)(BTf + (size_t)((ks*16 + w*2  )*512) + l*8);
    B1[ks] = *(const bf16x8*)(BTf + (size_t)((ks*16 + w*2+1)*512) + l*8);
  }
  const int c0 = w*32 + lr, c1 = w*32 + 16 + lr;
  float b0 = 0.f, b1 = 0.f;
  if (mode == 1){ b0 = bias[c0]; b1 = bias[c1]; }

  for (int grp = blockIdx.x; grp < ngrp; grp += gridDim.x){
    const int vb = grp*GRP;
    // ---- phase A: each wave seg-sums 8 nodes (rows w*8 .. w*8+7)
    #pragma unroll 2
    for (int hh=0; hh<8; hh++){
      int v = vb + w*8 + hh;
      float a[4] = {0.f,0.f,0.f,0.f};
      if (v < N){
        uint2 av = *(const uint2*)(alpha16 + (size_t)v*HD + l*4);
        a[0]=b2f((u16)av.x); a[1]=b2f((u16)(av.x>>16));
        a[2]=b2f((u16)av.y); a[3]=b2f((u16)(av.y>>16));
        int s = start_d[v] - KBIAS, e2 = start_d[v+1] - KBIAS;
        int cnt = e2 - s;
        const u16* Ir0 = I + (size_t)s*HD + l*4;
        if (Vprev){
          const int* sp = esrc_p + s;
          int done = 0;
          while (done < cnt){
            int m = min(64, cnt - done);
            int idx = (l < m) ? sp[done + l] : 0;   // batched coalesced index prefetch
            int j = 0;
            for (; j+2 <= m; j+=2){
              int s0 = __shfl(idx, j), s1 = __shfl(idx, j+1);
              uint2 i0 = *(const uint2*)(Ir0 + (size_t)(done+j  )*HD);
              uint2 i1 = *(const uint2*)(Ir0 + (size_t)(done+j+1)*HD);
              uint2 v0 = *(const uint2*)(Vprev + (size_t)s0*HD + l*4);
              uint2 v1 = *(const uint2*)(Vprev + (size_t)s1*HD + l*4);
              racc2(a, i0, v0); racc2(a, i1, v1);
            }
            if (j < m){
              int s0 = __shfl(idx, j);
              uint2 i0 = *(const uint2*)(Ir0 + (size_t)(done+j)*HD);
              uint2 v0 = *(const uint2*)(Vprev + (size_t)s0*HD + l*4);
              racc2(a, i0, v0);
            }
            done += m;
          }
        } else {
          int j = 0;
          for (; j+2 <= cnt; j+=2){
            uint2 i0 = *(const uint2*)(Ir0 + (size_t)j*HD);
            uint2 i1 = *(const uint2*)(Ir0 + (size_t)(j+1)*HD);
            racc1(a, i0); racc1(a, i1);
          }
          if (j < cnt) racc1(a, *(const uint2*)(Ir0 + (size_t)j*HD));
        }
      }
      ushort4 o; o.x=f2b(a[0]); o.y=f2b(a[1]); o.z=f2b(a[2]); o.w=f2b(a[3]);
      if (v < N && Sout) *(ushort4*)(Sout + (size_t)v*HD + l*4) = o;
      *(ushort4*)&A_lds[w*8+hh][l*4] = o;
    }
    __syncthreads();
    // ---- phase B: 4 row-tiles of 16, MFMA vs register B
    #pragma unroll
    for (int t4=0; t4<4; t4++){
      f32x4 acc0 = (f32x4){0.f,0.f,0.f,0.f};
      f32x4 acc1 = (f32x4){0.f,0.f,0.f,0.f};
      const u16* Ar = &A_lds[t4*16 + lr][0];
      #pragma unroll
      for (int ks=0; ks<8; ks++){
        bf16x8 af = *(const bf16x8*)(Ar + ks*32 + lq*8);
        acc0 = __builtin_amdgcn_mfma_f32_16x16x32_bf16(af, B0[ks], acc0, 0,0,0);
        acc1 = __builtin_amdgcn_mfma_f32_16x16x32_bf16(af, B1[ks], acc1, 0,0,0);
      }
      #pragma unroll
      for (int reg=0; reg<4; reg++){
        int gm = vb + t4*16 + lq*4 + reg;
        if (gm < N){
          if (mode == 1){
            float v0 = acc0[reg] + b2f(Radd[(size_t)gm*HD + c0]) + b0;
            float v1 = acc1[reg] + b2f(Radd[(size_t)gm*HD + c1]) + b1;
            hout[(size_t)gm*HD + c0] = v0 > 0.f ? v0 : 0.f;
            hout[(size_t)gm*HD + c1] = v1 > 0.f ? v1 : 0.f;
          } else {
            Vout[(size_t)gm*HD + c0] = f2b(acc0[reg]);
            Vout[(size_t)gm*HD + c1] = f2b(acc1[reg]);
          }
        }
      }
    }
    __syncthreads();
  }
}

// ---------------- fused backtracking correction (non-final): corr1 + corrV ----------------
// Single block, np ~16 expected. Part 1 mirrors k_corr1 exactly (old-msgA snapshot),
// commit, then part 2 mirrors k_corrV (additive V patch per distinct dst).
__global__ __launch_bounds__(256, 1) void k_corr_nf(
    const u16* __restrict__ I, const u16* __restrict__ Vprev,
    const int* __restrict__ esrc_p, const int* __restrict__ edst_p,
    const int2* __restrict__ pairs, const int* __restrict__ npairs_p,
    const float* __restrict__ Wh, float* __restrict__ msgA,
    float* __restrict__ newA, float* __restrict__ deltaS,
    u16* __restrict__ Vcur)
{
  int np = *npairs_p; if (np > CORR_CAP) np = CORR_CAP;
  if (np == 0) return;
  int t = threadIdx.x;
  __shared__ float cs[HD];
  // ---- part 1: per first-occurrence edge, deltaS = m_true - m_naive; newA = m_true
  for (int p=0; p<np; p++){
    int e = pairs[p].x;
    bool first = true;                      // block-uniform
    for (int q=0;q<p;q++) if (pairs[q].x == e){ first=false; break; }
    if (first){
      float c = 0.f;
      for (int q=p;q<np;q++) if (pairs[q].x == e) c += msgA[(size_t)q*HD + t];
      cs[t] = c;
    }
    __syncthreads();
    if (first){
      float a0=0.f,a1=0.f,a2=0.f,a3=0.f;
      for (int k=0;k<HD;k+=4){
        a0 += cs[k]  *Wh[(size_t)k*HD+t];
        a1 += cs[k+1]*Wh[(size_t)(k+1)*HD+t];
        a2 += cs[k+2]*Wh[(size_t)(k+2)*HD+t];
        a3 += cs[k+3]*Wh[(size_t)(k+3)*HD+t];
      }
      float corr = (a0+a1)+(a2+a3);
      int u = esrc_p[e];
      float base = b2f(I[(size_t)e*HD + t]) + b2f(Vprev[(size_t)u*HD + t]);
      float mn = base > 0.f ? base : 0.f;
      float bt = base - corr;
      float mt = bt > 0.f ? bt : 0.f;
      deltaS[(size_t)p*HD + t] = mt - mn;
      for (int q=0;q<np;q++) if (pairs[q].y == e) newA[(size_t)q*HD + t] = mt;
    }
    __syncthreads();
  }
  // commit msgA for next iteration
  for (int p=0;p<np;p++) msgA[(size_t)p*HD + t] = newA[(size_t)p*HD + t];
  __syncthreads();
  // ---- part 2: per distinct affected dst, V[dv] += (sum first-occurrence deltaS)@Wh
  for (int p=0; p<np; p++){
    int dv = edst_p[pairs[p].x];
    bool firstdv = true;                    // block-uniform
    for (int q=0;q<p;q++) if (edst_p[pairs[q].x] == dv){ firstdv=false; break; }
    if (firstdv){
      float d = 0.f;
      for (int q=p;q<np;q++){
        if (edst_p[pairs[q].x] != dv) continue;
        bool fe = true;
        for (int r=0;r<q;r++) if (pairs[r].x == pairs[q].x){ fe=false; break; }
        if (fe) d += deltaS[(size_t)q*HD + t];
      }
      cs[t] = d;
    }
    __syncthreads();
    if (firstdv){
      float a0=0.f,a1=0.f,a2=0.f,a3=0.f;
      for (int k=0;k<HD;k+=4){
        a0 += cs[k]  *Wh[(size_t)k*HD+t];
        a1 += cs[k+1]*Wh[(size_t)(k+1)*HD+t];
        a2 += cs[k+2]*Wh[(size_t)(k+2)*HD+t];
        a3 += cs[k+3]*Wh[(size_t)(k+3)*HD+t];
      }
      float dot = (a0+a1)+(a2+a3);
      u16* vp = Vcur + (size_t)dv*HD + t;
      *vp = f2b(b2f(*vp) + dot);
    }
    __syncthreads();
  }
}

// ---------------- fused backtracking correction (final): corr1 + corr2 + corr3 ----------------
__global__ __launch_bounds__(256, 1) void k_corr_fin(
    const u16* __restrict__ I, const u16* __restrict__ Vprev,
    const int* __restrict__ esrc_p, const int* __restrict__ edst_p,
    const int2* __restrict__ pairs, const int* __restrict__ npairs_p,
    const float* __restrict__ Wh, float* __restrict__ msgA,
    float* __restrict__ newA, float* __restrict__ deltaS,
    u16* __restrict__ Scur, const float* __restrict__ Wob,
    const u16* __restrict__ Radd, const float* __restrict__ bias,
    float* __restrict__ hout)
{
  int np = *npairs_p; if (np > CORR_CAP) np = CORR_CAP;
  if (np == 0) return;
  int t = threadIdx.x;
  __shared__ float cs[HD];
  // ---- part 1 (== corr1)
  for (int p=0; p<np; p++){
    int e = pairs[p].x;
    bool first = true;
    for (int q=0;q<p;q++) if (pairs[q].x == e){ first=false; break; }
    if (first){
      float c = 0.f;
      for (int q=p;q<np;q++) if (pairs[q].x == e) c += msgA[(size_t)q*HD + t];
      cs[t] = c;
    }
    __syncthreads();
    if (first){
      float a0=0.f,a1=0.f,a2=0.f,a3=0.f;
      for (int k=0;k<HD;k+=4){
        a0 += cs[k]  *Wh[(size_t)k*HD+t];
        a1 += cs[k+1]*Wh[(size_t)(k+1)*HD+t];
        a2 += cs[k+2]*Wh[(size_t)(k+2)*HD+t];
        a3 += cs[k+3]*Wh[(size_t)(k+3)*HD+t];
      }
      float corr = (a0+a1)+(a2+a3);
      int u = esrc_p[e];
      float base = b2f(I[(size_t)e*HD + t]) + b2f(Vprev[(size_t)u*HD + t]);
      float mn = base > 0.f ? base : 0.f;
      float bt = base - corr;
      float mt = bt > 0.f ? bt : 0.f;
      deltaS[(size_t)p*HD + t] = mt - mn;
      for (int q=0;q<np;q++) if (pairs[q].y == e) newA[(size_t)q*HD + t] = mt;
    }
    __syncthreads();
  }
  // ---- part 2 (== corr2): commit msgA; apply deltaS to Scur (serial, shared-dst safe)
  for (int p=0; p<np; p++){
    msgA[(size_t)p*HD + t] = newA[(size_t)p*HD + t];
    int e = pairs[p].x;
    bool first = true;
    for (int q=0;q<p;q++) if (pairs[q].x == e){ first=false; break; }
    if (first){
      int dv = edst_p[e];
      u16* sp = Scur + (size_t)dv*HD + t;
      *sp = f2b(b2f(*sp) + deltaS[(size_t)p*HD + t]);
    }
    __syncthreads();
  }
  // ---- part 3 (== corr3): recompute h rows for distinct affected dst
  for (int p=0; p<np; p++){
    int dv = edst_p[pairs[p].x];
    bool first = true;
    for (int q=0;q<p;q++) if (edst_p[pairs[q].x] == dv){ first=false; break; }
    if (first) cs[t] = b2f(Scur[(size_t)dv*HD + t]);
    __syncthreads();
    if (first){
      float a0=0.f,a1=0.f,a2=0.f,a3=0.f;
      for (int k=0;k<HD;k+=4){
        a0 += cs[k]  *Wob[(size_t)k*HD+t];
        a1 += cs[k+1]*Wob[(size_t)(k+1)*HD+t];
        a2 += cs[k+2]*Wob[(size_t)(k+2)*HD+t];
        a3 += cs[k+3]*Wob[(size_t)(k+3)*HD+t];
      }
      float acc = (a0+a1)+(a2+a3);
      float hv = acc + b2f(Radd[(size_t)dv*HD + t]) + bias[t];
      hout[(size_t)dv*HD + t] = hv > 0.f ? hv : 0.f;
    }
    __syncthreads();
  }
}

// ---------------- graph mean (graph_ids sorted), fp32 in/out ----------------
__global__ void k_graph_mean(const float* __restrict__ h, const int* __restrict__ gid,
                             int N, int G, float* __restrict__ out){
  int g = (int)(((long long)blockIdx.x*blockDim.x + threadIdx.x)>>6);
  int l = threadIdx.x & 63;
  if (g >= G) return;
  int lo=0, hi=N;
  while (lo<hi){ int mid=(lo+hi)>>1; if (gid[mid] < g) lo=mid+1; else hi=mid; }
  int b = lo;
  hi = N;
  while (lo<hi){ int mid=(lo+hi)>>1; if (gid[mid] < g+1) lo=mid+1; else hi=mid; }
  int e2 = lo;
  float a0=0.f,a1=0.f,a2=0.f,a3=0.f;
  for (int v=b; v<e2; v++){
    float4 hv = *(const float4*)(h + (size_t)v*HD + l*4);
    a0 += hv.x; a1 += hv.y; a2 += hv.z; a3 += hv.w;
  }
  int cnt = e2 - b; if (cnt < 1) cnt = 1;
  float inv = 1.0f/(float)cnt;
  float4 o; o.x=a0*inv; o.y=a1*inv; o.z=a2*inv; o.w=a3*inv;
  *(float4*)(out + (size_t)g*HD + l*4) = o;
}

extern "C" void kernel_launch(void* const* d_in, const int* in_sizes, int n_in,
                              void* d_out, int out_size, void* d_ws, size_t ws_size,
                              hipStream_t stream){
  const float* x_nodes = (const float*)d_in[0];
  const float* x_edges = (const float*)d_in[1];
  const float* tree_m  = (const float*)d_in[2];
  const float* W_i     = (const float*)d_in[3];
  const float* W_h     = (const float*)d_in[4];
  const float* W_o     = (const float*)d_in[5];
  const float* b_o     = (const float*)d_in[6];
  const int* edge_src = (const int*)d_in[7];
  const int* edge_dst = (const int*)d_in[8];
  const int* tgt      = (const int*)d_in[11];
  const int* teid     = (const int*)d_in[12];
  const int* gid      = (const int*)d_in[13];

  const int N = in_sizes[0]/35;
  const int E = in_sizes[1]/5;
  const int K = in_sizes[11];
  const int G = out_size/HD;
  const int N2 = 2*N;

  // ---- workspace layout (~277 MB) ----
  char* wsb = (char*)d_ws;
  auto align256 = [](size_t x){ return (x + 255) & ~(size_t)255; };
  size_t oI      = 0;                                          // 102.4 MB
  size_t oSa     = oI      + align256((size_t)E*HD*2);         // 25.6 MB
  size_t oVa     = oSa     + align256((size_t)N*HD*2);         // 25.6 MB
  size_t oP      = oVa     + align256((size_t)N*HD*2);         // 25.6 MB (hbuf lo)
  size_t oVb     = oP      + align256((size_t)N*HD*2);         // 25.6 MB (hbuf hi)
  size_t oR      = oVb     + align256((size_t)N*HD*2);         // 25.6 MB
  size_t oAlpha  = oR      + align256((size_t)N*HD*2);         // 25.6 MB
  size_t oXnf    = oAlpha  + align256((size_t)N*HD*2);         // 6.4 MB
  size_t oXep    = oXnf    + align256((size_t)N*64*2);         // 4.0 MB
  size_t oBTP    = oXep    + align256((size_t)E*5*4);
  size_t oBTWh   = oBTP    + align256((size_t)2*16*512*2);
  size_t oBTRa   = oBTWh   + align256((size_t)8*16*512*2);
  size_t oBTWob  = oBTRa   + align256((size_t)2*16*512*2);
  size_t oDeg2   = oBTWob  + align256((size_t)8*16*512*2);     // 2N+1 ints ([2N]=npairs)
  size_t oStart2 = oDeg2   + align256((size_t)(N2+1)*4);       // 2N+1 ints
  size_t oCur2   = oStart2 + align256((size_t)(N2+1)*4);       // 2N ints
  size_t oBuk2   = oCur2   + align256((size_t)N2*4);           // K+E ints
  size_t oEsrcP  = oBuk2   + align256((size_t)(K+E)*4);
  size_t oEdstP  = oEsrcP  + align256((size_t)E*4);
  size_t oBsum   = oEdstP  + align256((size_t)E*4);
  size_t oPairs  = oBsum   + align256((size_t)1024*4);
  size_t oMsgA   = oPairs  + align256((size_t)CORR_CAP*8);     // 2 MB
  size_t oNewA   = oMsgA   + align256((size_t)CORR_CAP*HD*4);  // 2 MB
  size_t oDeltaS = oNewA   + align256((size_t)CORR_CAP*HD*4);  // 2 MB

  u16*   I       = (u16*)(wsb + oI);
  u16*   Sa      = (u16*)(wsb + oSa);
  u16*   Va      = (u16*)(wsb + oVa);
  u16*   P       = (u16*)(wsb + oP);
  u16*   Vb      = (u16*)(wsb + oVb);
  u16*   R       = (u16*)(wsb + oR);
  u16*   alpha16 = (u16*)(wsb + oAlpha);
  u16*   xnf     = (u16*)(wsb + oXnf);
  float* xep     = (float*)(wsb + oXep);
  u16*   BT_P    = (u16*)(wsb + oBTP);
  u16*   BT_Wh   = (u16*)(wsb + oBTWh);
  u16*   BT_Ra   = (u16*)(wsb + oBTRa);
  u16*   BT_Wob  = (u16*)(wsb + oBTWob);
  int*   deg2    = (int*)(wsb + oDeg2);
  int*   npairs  = deg2 + N2;                 // zeroed in k_prep_all
  int*   start2  = (int*)(wsb + oStart2);
  int*   cursor2 = (int*)(wsb + oCur2);
  int*   bucket2 = (int*)(wsb + oBuk2);
  int*   esrc_p  = (int*)(wsb + oEsrcP);
  int*   edst_p  = (int*)(wsb + oEdstP);
  int*   bsum    = (int*)(wsb + oBsum);
  int2*  pairs   = (int2*)(wsb + oPairs);
  float* msgA    = (float*)(wsb + oMsgA);
  float* newA    = (float*)(wsb + oNewA);
  float* deltaS  = (float*)(wsb + oDeltaS);
  // hbuf (N*HD fp32 = 51.2 MB) overlays P+Vb: P dead after build_I, Vb dead after call2
  float* hbuf    = (float*)(wsb + oP);

  const int egrid256 = (E+255)/256;
  const int kgrid256 = (K+255)/256;
  const int nb2      = (N2+255)/256;                    // 391 <= 1024
  const int zb       = (N2+1+255)/256;
  const int xnfb     = (int)(((size_t)N*64+255)/256);
  const int agrid    = (N+3)/4;
  const int ngrp     = (N+GRP-1)/GRP;

  // ---- fused prep: B tables + xnf + zero(deg2,npairs)
  k_prep_all<<<640+zb+xnfb, 256, 0, stream>>>(W_i, W_h, W_o, x_nodes,
                                              BT_P, BT_Wh, BT_Ra, BT_Wob,
                                              xnf, deg2, N, zb);
  // ---- concatenated histograms + single scan + fused fills
  k_hist2<<<kgrid256+egrid256, 256, 0, stream>>>(tgt, edge_dst, deg2, K, E, N, kgrid256);
  k_scan_p1<<<nb2, 256, 0, stream>>>(deg2, N2, bsum);
  k_scan_p2<<<1, 1024, 0, stream>>>(bsum, nb2, start2 + N2);   // start2[2N] = K+E
  k_scan_p3<<<nb2, 256, 0, stream>>>(deg2, bsum, N2, start2, cursor2);
  k_fill2<<<kgrid256+egrid256, 256, 0, stream>>>(tgt, teid, edge_dst, cursor2, bucket2,
                                                 K, E, N, kgrid256);
  k_perm_xep<<<egrid256, 256, 0, stream>>>(bucket2, K, edge_src, edge_dst, x_edges,
                                           esrc_p, edst_p, xep, E);
  k_alpha_pairs<<<agrid+egrid256, 256, 0, stream>>>(tree_m, start2, bucket2, alpha16,
                                                    esrc_p, edst_p, npairs, pairs,
                                                    N, E, K, agrid);
  // ---- P = xn@Wi_a, R = xn@Wo_a
  k_pr2<<<512, 512, 0, stream>>>(xnf, BT_P, BT_Ra, P, R, N);
  // ---- I = P[src] + xe@Wi_b (pre-relu); msgA = msg_0 of partner edges
  k_build_I<<<2048, 256, 0, stream>>>(P, xep, esrc_p, W_i, I, E);
  k_msgA0<<<64, 256, 0, stream>>>(I, pairs, npairs, msgA);

  const float* Wob = W_o + 35*HD;
  const int* start_d = start2 + N;   // absolute, bias K

  // ---- call0: S_0 = alpha + sum relu(I); V_0 = S_0@Wh  (exact, no correction)
  k_bp<<<ngrp, 512, 0, stream>>>(I, (const u16*)0, alpha16, start_d, K, esrc_p, BT_Wh,
                                 (const u16*)0, (const float*)0,
                                 (u16*)0, Va, (float*)0, N, 0);
  // ---- call1: V_0 -> V_1 (Vb); fused correction
  k_bp<<<ngrp, 512, 0, stream>>>(I, Va, alpha16, start_d, K, esrc_p, BT_Wh,
                                 (const u16*)0, (const float*)0,
                                 (u16*)0, Vb, (float*)0, N, 0);
  k_corr_nf<<<1, 256, 0, stream>>>(I, Va, esrc_p, edst_p, pairs, npairs, W_h,
                                   msgA, newA, deltaS, Vb);
  // ---- call2: V_1 -> V_2 (Va); fused correction
  k_bp<<<ngrp, 512, 0, stream>>>(I, Vb, alpha16, start_d, K, esrc_p, BT_Wh,
                                 (const u16*)0, (const float*)0,
                                 (u16*)0, Va, (float*)0, N, 0);
  k_corr_nf<<<1, 256, 0, stream>>>(I, Vb, esrc_p, edst_p, pairs, npairs, W_h,
                                   msgA, newA, deltaS, Va);
  // ---- call3 (final): h = relu(R + S_3@Wo_b + b); fused S-based correction
  k_bp<<<ngrp, 512, 0, stream>>>(I, Va, alpha16, start_d, K, esrc_p, BT_Wob,
                                 R, b_o, Sa, (u16*)0, hbuf, N, 1);
  k_corr_fin<<<1, 256, 0, stream>>>(I, Va, esrc_p, edst_p, pairs, npairs, W_h,
                                    msgA, newA, deltaS, Sa, Wob, R, b_o, hbuf);

  k_graph_mean<<<(G+3)/4, 256, 0, stream>>>(hbuf, gid, N, G, (float*)d_out);
}

// Round 12
// 621.719 us; speedup vs baseline: 1.5888x; 1.5888x over previous
//
#include <hip/hip_runtime.h>
#include <stdint.h>

typedef unsigned short u16;
typedef __attribute__((ext_vector_type(8))) short bf16x8;
typedef __attribute__((ext_vector_type(4))) float f32x4;

#define HD 256
#define AST 264       // A_lds row stride in u16 (528 B: 16B-aligned, bank-rotating)
#define GRP 64        // nodes per block-iteration in k_bp
#define CORR_CAP 2048 // backtracking-pair capacity (expected ~16 for this graph)

static __device__ __forceinline__ float b2f(u16 x){
  union{float f; unsigned u;} v; v.u = ((unsigned)x)<<16; return v.f;
}
static __device__ __forceinline__ u16 f2b(float f){
  union{float f; unsigned u;} v; v.f = f;
  unsigned r = v.u + 0x7fffu + ((v.u>>16)&1u);
  return (u16)(r>>16);
}
// accumulate relu(I + V) (both bf16 pairs) into a[4]
static __device__ __forceinline__ void racc2(float* a, uint2 iv, uint2 vv){
  float t0 = b2f((u16)iv.x)       + b2f((u16)vv.x);
  float t1 = b2f((u16)(iv.x>>16)) + b2f((u16)(vv.x>>16));
  float t2 = b2f((u16)iv.y)       + b2f((u16)vv.y);
  float t3 = b2f((u16)(iv.y>>16)) + b2f((u16)(vv.y>>16));
  a[0] += t0>0.f?t0:0.f; a[1] += t1>0.f?t1:0.f;
  a[2] += t2>0.f?t2:0.f; a[3] += t3>0.f?t3:0.f;
}
static __device__ __forceinline__ void racc1(float* a, uint2 iv){
  float t0 = b2f((u16)iv.x), t1 = b2f((u16)(iv.x>>16));
  float t2 = b2f((u16)iv.y), t3 = b2f((u16)(iv.y>>16));
  a[0] += t0>0.f?t0:0.f; a[1] += t1>0.f?t1:0.f;
  a[2] += t2>0.f?t2:0.f; a[3] += t3>0.f?t3:0.f;
}

// ---------------- fused prep: 4 B-tables + xnf + zero(deg2 incl npairs) ----------------
static __device__ __forceinline__ void prep_frag_body(const float* __restrict__ W,
    int k0, int kmax, u16* __restrict__ out, int lb, int tid){
  int g = lb*256 + tid;
  int i = g & 7, l = (g>>3)&63, t = g>>9;
  int nj = t & 15, ks = t >> 4;
  int n = nj*16 + (l&15);
  int k = ks*32 + (l>>4)*8 + i;
  float v = (k < kmax) ? W[(size_t)(k0+k)*HD + n] : 0.f;
  out[g] = f2b(v);
}
__global__ void k_prep_all(const float* __restrict__ Wi, const float* __restrict__ Wh,
                           const float* __restrict__ Wo, const float* __restrict__ xn,
                           u16* __restrict__ BT_P, u16* __restrict__ BT_Wh,
                           u16* __restrict__ BT_Ra, u16* __restrict__ BT_Wob,
                           u16* __restrict__ xnf, int* __restrict__ deg2,
                           int N, int zb){
  int b = blockIdx.x, tid = threadIdx.x;
  if (b < 64){ prep_frag_body(Wi, 0, 35, BT_P, b, tid); return; }
  b -= 64;
  if (b < 256){ prep_frag_body(Wh, 0, 256, BT_Wh, b, tid); return; }
  b -= 256;
  if (b < 64){ prep_frag_body(Wo, 0, 35, BT_Ra, b, tid); return; }
  b -= 64;
  if (b < 256){ prep_frag_body(Wo, 35, 256, BT_Wob, b, tid); return; }
  b -= 256;
  if (b < zb){
    int i = b*256 + tid;
    if (i < 2*N+1) deg2[i] = 0;
    return;
  }
  b -= zb;
  { // xnf
    long long g = (long long)b*256 + tid;
    int v2 = (int)(g >> 6), c = (int)(g & 63);
    if (v2 >= N) return;
    float v = (c < 35) ? xn[(size_t)v2*35 + c] : 0.f;
    xnf[g] = f2b(v);
  }
}

// ---------------- fused histograms: tgt -> deg2[0..N), dst -> deg2[N..2N) ----------------
__global__ void k_hist2(const int* __restrict__ tgt, const int* __restrict__ edst,
                        int* __restrict__ deg2, int K, int E, int N, int kgrid){
  int b = blockIdx.x;
  if (b < kgrid){
    int i = b*256 + threadIdx.x;
    if (i < K) atomicAdd(&deg2[tgt[i]], 1);
  } else {
    int i = (b-kgrid)*256 + threadIdx.x;
    if (i < E) atomicAdd(&deg2[N + edst[i]], 1);
  }
}

// ---------------- 3-phase parallel exclusive scan ----------------
__global__ void k_scan_p1(const int* __restrict__ deg, int n, int* __restrict__ bsum){
  int i = blockIdx.x*256 + threadIdx.x;
  int v = (i < n) ? deg[i] : 0;
  #pragma unroll
  for (int o=32; o>0; o>>=1) v += __shfl_down(v, o);
  __shared__ int w[4];
  if ((threadIdx.x&63)==0) w[threadIdx.x>>6] = v;
  __syncthreads();
  if (threadIdx.x==0) bsum[blockIdx.x] = w[0]+w[1]+w[2]+w[3];
}
__global__ __launch_bounds__(1024) void k_scan_p2(int* __restrict__ bsum, int nb,
                                                  int* __restrict__ total_dst){
  __shared__ int sm[1024];
  int t = threadIdx.x;
  int v = (t < nb) ? bsum[t] : 0;
  sm[t] = v; __syncthreads();
  for (int o=1; o<1024; o<<=1){
    int u = (t>=o) ? sm[t-o] : 0;
    __syncthreads();
    sm[t] += u;
    __syncthreads();
  }
  if (t < nb) bsum[t] = sm[t] - v;
  if (t == 1023 && total_dst) *total_dst = sm[1023];
}
__global__ void k_scan_p3(const int* __restrict__ deg, const int* __restrict__ bsum, int n,
                          int* __restrict__ start, int* __restrict__ cursor){
  int t = threadIdx.x;
  int i = blockIdx.x*256 + t;
  int v = (i < n) ? deg[i] : 0;
  __shared__ int sm[256];
  sm[t] = v; __syncthreads();
  for (int o=1; o<256; o<<=1){
    int u = (t>=o) ? sm[t-o] : 0;
    __syncthreads();
    sm[t] += u;
    __syncthreads();
  }
  int ex = sm[t] - v + bsum[blockIdx.x];
  if (i < n){ start[i] = ex; cursor[i] = ex; }
}

// ---------------- fused fills: tgt buckets [0,K), dst buckets [K,K+E) ----------------
__global__ void k_fill2(const int* __restrict__ tgt, const int* __restrict__ teid,
                        const int* __restrict__ edst, int* __restrict__ cursor2,
                        int* __restrict__ bucket2, int K, int E, int N, int kgrid){
  int b = blockIdx.x;
  if (b < kgrid){
    int i = b*256 + threadIdx.x;
    if (i >= K) return;
    int pos = atomicAdd(&cursor2[tgt[i]], 1);
    bucket2[pos] = teid[i];
  } else {
    int e = (b-kgrid)*256 + threadIdx.x;
    if (e >= E) return;
    int pos = atomicAdd(&cursor2[N + edst[e]], 1);
    bucket2[pos] = e;   // original edge id; absolute pos in [K, K+E)
  }
}

// ---------------- permuted edge arrays + xep (new label = dst-sorted rank) ----------------
__global__ void k_perm_xep(const int* __restrict__ bucket2, int K,
                           const int* __restrict__ esrc, const int* __restrict__ edst,
                           const float* __restrict__ xe,
                           int* __restrict__ esrc_p, int* __restrict__ edst_p,
                           float* __restrict__ xep, int E){
  int e = blockIdx.x*256 + threadIdx.x;
  if (e >= E) return;
  int o = bucket2[K + e];
  esrc_p[e] = esrc[o];
  edst_p[e] = edst[o];
  #pragma unroll
  for (int k=0;k<5;k++) xep[(size_t)e*5+k] = xe[(size_t)o*5+k];
}

// ---------------- fused alpha gather + backtracking pair list ----------------
__global__ void k_alpha_pairs(const float* __restrict__ tree_m,
                              const int* __restrict__ start2, const int* __restrict__ bucket2,
                              u16* __restrict__ alpha16,
                              const int* __restrict__ esrc_p, const int* __restrict__ edst_p,
                              int* __restrict__ npairs, int2* __restrict__ pairs,
                              int N, int E, int K, int agrid){
  int b = blockIdx.x;
  if (b < agrid){
    int v = (int)(((long long)b*256 + threadIdx.x)>>6);
    int l = threadIdx.x & 63;
    if (v >= N) return;
    int s = start2[v], e2 = start2[v+1];     // absolute into bucket2 (tgt part)
    float a0=0.f,a1=0.f,a2=0.f,a3=0.f;
    for (int j=s;j<e2;j++){
      float4 tv = *(const float4*)(tree_m + (size_t)bucket2[j]*HD + l*4);
      a0 += tv.x; a1 += tv.y; a2 += tv.z; a3 += tv.w;
    }
    ushort4 o; o.x=f2b(a0); o.y=f2b(a1); o.z=f2b(a2); o.w=f2b(a3);
    *(ushort4*)(alpha16 + (size_t)v*HD + l*4) = o;
  } else {
    int e = (b-agrid)*256 + threadIdx.x;
    if (e >= E) return;
    int u = esrc_p[e], v = edst_p[e];
    int s = start2[N+u] - K, t = start2[N+u+1] - K;
    for (int ep=s; ep<t; ep++){
      if (esrc_p[ep] == v){
        int pos = atomicAdd(npairs, 1);
        if (pos < CORR_CAP) pairs[pos] = (int2){e, ep};
      }
    }
  }
}

// ---------------- fused P/R GEMM: P = xnf@Wi_a, R = xnf@Wo_a ----------------
__global__ __launch_bounds__(512, 4) void k_pr2(
    const u16* __restrict__ xnf, const u16* __restrict__ BT_P,
    const u16* __restrict__ BT_Ra, u16* __restrict__ P, u16* __restrict__ R, int M)
{
  const int tid = threadIdx.x;
  const int w = tid>>6, l = tid&63;
  const int lr = l&15, lq = l>>4;
  const int nrb = (M+15)>>4;
  bf16x8 BP0[2], BP1[2], BR0[2], BR1[2];
  #pragma unroll
  for (int ks=0; ks<2; ks++){
    BP0[ks] = *(const bf16x8*)(BT_P  + (size_t)((ks*16 + w*2  )*512) + l*8);
    BP1[ks] = *(const bf16x8*)(BT_P  + (size_t)((ks*16 + w*2+1)*512) + l*8);
    BR0[ks] = *(const bf16x8*)(BT_Ra + (size_t)((ks*16 + w*2  )*512) + l*8);
    BR1[ks] = *(const bf16x8*)(BT_Ra + (size_t)((ks*16 + w*2+1)*512) + l*8);
  }
  const int c0 = w*32 + lr, c1 = w*32 + 16 + lr;
  for (int rb = blockIdx.x; rb < nrb; rb += gridDim.x){
    int r = rb*16 + lr; int rc = min(r, M-1);
    const u16* fr = xnf + (size_t)rc*64 + lq*8;
    bf16x8 a0 = *(const bf16x8*)(fr);
    bf16x8 a1 = *(const bf16x8*)(fr + 32);
    f32x4 p0={0.f,0.f,0.f,0.f}, p1={0.f,0.f,0.f,0.f};
    f32x4 r0={0.f,0.f,0.f,0.f}, r1={0.f,0.f,0.f,0.f};
    p0 = __builtin_amdgcn_mfma_f32_16x16x32_bf16(a0, BP0[0], p0, 0,0,0);
    p0 = __builtin_amdgcn_mfma_f32_16x16x32_bf16(a1, BP0[1], p0, 0,0,0);
    p1 = __builtin_amdgcn_mfma_f32_16x16x32_bf16(a0, BP1[0], p1, 0,0,0);
    p1 = __builtin_amdgcn_mfma_f32_16x16x32_bf16(a1, BP1[1], p1, 0,0,0);
    r0 = __builtin_amdgcn_mfma_f32_16x16x32_bf16(a0, BR0[0], r0, 0,0,0);
    r0 = __builtin_amdgcn_mfma_f32_16x16x32_bf16(a1, BR0[1], r0, 0,0,0);
    r1 = __builtin_amdgcn_mfma_f32_16x16x32_bf16(a0, BR1[0], r1, 0,0,0);
    r1 = __builtin_amdgcn_mfma_f32_16x16x32_bf16(a1, BR1[1], r1, 0,0,0);
    #pragma unroll
    for (int reg=0; reg<4; reg++){
      int gm = rb*16 + lq*4 + reg;
      if (gm < M){
        P[(size_t)gm*HD + c0] = f2b(p0[reg]);
        P[(size_t)gm*HD + c1] = f2b(p1[reg]);
        R[(size_t)gm*HD + c0] = f2b(r0[reg]);
        R[(size_t)gm*HD + c1] = f2b(r1[reg]);
      }
    }
  }
}

// ---------------- I[e] = P[src[e]] + xe[e]@Wi[35:40]  (pre-relu, bf16) ----------------
__global__ __launch_bounds__(256, 8) void k_build_I(
    const u16* __restrict__ P, const float* __restrict__ xep,
    const int* __restrict__ esrc_p, const float* __restrict__ Wi,
    u16* __restrict__ I, int E)
{
  const int l = threadIdx.x & 63;
  const int wid = (blockIdx.x*256 + threadIdx.x) >> 6;
  const int nw = gridDim.x*4;
  float wq[5][4];
  #pragma unroll
  for (int k=0;k<5;k++){
    float4 t = *(const float4*)(Wi + (size_t)(35+k)*HD + l*4);
    wq[k][0]=t.x; wq[k][1]=t.y; wq[k][2]=t.z; wq[k][3]=t.w;
  }
  for (int e = wid; e < E; e += nw){
    int s = esrc_p[e];
    const float* xp = xep + (size_t)e*5;
    float x0=xp[0], x1=xp[1], x2=xp[2], x3=xp[3], x4=xp[4];
    uint2 uv = *(const uint2*)(P + (size_t)s*HD + l*4);
    float v[4] = { b2f((u16)uv.x), b2f((u16)(uv.x>>16)),
                   b2f((u16)uv.y), b2f((u16)(uv.y>>16)) };
    #pragma unroll
    for (int j=0;j<4;j++)
      v[j] += x0*wq[0][j] + x1*wq[1][j] + x2*wq[2][j] + x3*wq[3][j] + x4*wq[4][j];
    ushort4 o; o.x=f2b(v[0]); o.y=f2b(v[1]); o.z=f2b(v[2]); o.w=f2b(v[3]);
    *(ushort4*)(I + (size_t)e*HD + l*4) = o;
  }
}

// msgA[p] = relu(I[pairs[p].y])  (msg_0 of partner edges)
__global__ void k_msgA0(const u16* __restrict__ I, const int2* __restrict__ pairs,
                        const int* __restrict__ npairs_p, float* __restrict__ msgA){
  int np = *npairs_p; if (np > CORR_CAP) np = CORR_CAP;
  int t = threadIdx.x;
  for (int p = blockIdx.x; p < np; p += gridDim.x){
    int ep = pairs[p].y;
    float v = b2f(I[(size_t)ep*HD + t]);
    msgA[(size_t)p*HD + t] = v > 0.f ? v : 0.f;
  }
}

// ---------------- fused BP step: per node v ----------------
// S[v] = alpha[v] + sum_{in-edges e} relu(I[e] + Vprev[src[e]])   (Vprev NULL -> relu(I))
// start_d entries are absolute (+KBIAS); edge labels are (value - KBIAS).
// mode 0: Vout[v] = S[v]@BTf (bf16)      mode 1: hout = relu(Radd + S@BTf + bias); Sout written
// NOTE: launch_bounds min-waves MUST stay 4 — at 8 the 64 B-frag VGPRs spill to scratch
// (round-8 regression). LDS-staged output + unroll-4 gathers REGRESSED (round-10).
// Single-block fused correction REGRESSED (round-11: 157us serial dots on 1 CU).
// This is the round-9 verified-best version.
__global__ __launch_bounds__(512, 4) void k_bp(
    const u16* __restrict__ I, const u16* __restrict__ Vprev,
    const u16* __restrict__ alpha16, const int* __restrict__ start_d, int KBIAS,
    const int* __restrict__ esrc_p, const u16* __restrict__ BTf,
    const u16* __restrict__ Radd, const float* __restrict__ bias,
    u16* __restrict__ Sout, u16* __restrict__ Vout, float* __restrict__ hout,
    int N, int mode)
{
  __shared__ u16 A_lds[GRP][AST];   // 33,792 B -> 4 blocks/CU (LDS-capped), 32 waves/CU
  const int tid = threadIdx.x;
  const int w = tid>>6, l = tid&63;
  const int lr = l&15, lq = l>>4;
  const int ngrp = (N+GRP-1)/GRP;

  bf16x8 B0[8], B1[8];
  #pragma unroll
  for (int ks=0; ks<8; ks++){
    B0[ks] = *(const bf16x8*)(BTf + (size_t)((ks*16 + w*2  )*512) + l*8);
    B1[ks] = *(const bf16x8*)(BTf + (size_t)((ks*16 + w*2 + 1)*512) + l*8);
  }
  const int c0 = w*32 + lr, c1 = w*32 + 16 + lr;
  float b0 = 0.f, b1 = 0.f;
  if (mode == 1){ b0 = bias[c0]; b1 = bias[c1]; }

  for (int grp = blockIdx.x; grp < ngrp; grp += gridDim.x){
    const int vb = grp*GRP;
    // ---- phase A: each wave seg-sums 8 nodes (rows w*8 .. w*8+7)
    #pragma unroll 2
    for (int hh=0; hh<8; hh++){
      int v = vb + w*8 + hh;
      float a[4] = {0.f,0.f,0.f,0.f};
      if (v < N){
        uint2 av = *(const uint2*)(alpha16 + (size_t)v*HD + l*4);
        a[0]=b2f((u16)av.x); a[1]=b2f((u16)(av.x>>16));
        a[2]=b2f((u16)av.y); a[3]=b2f((u16)(av.y>>16));
        int s = start_d[v] - KBIAS, e2 = start_d[v+1] - KBIAS;
        int cnt = e2 - s;
        const u16* Ir0 = I + (size_t)s*HD + l*4;
        if (Vprev){
          const int* sp = esrc_p + s;
          int done = 0;
          while (done < cnt){
            int m = min(64, cnt - done);
            int idx = (l < m) ? sp[done + l] : 0;   // batched coalesced index prefetch
            int j = 0;
            for (; j+2 <= m; j+=2){
              int s0 = __shfl(idx, j), s1 = __shfl(idx, j+1);
              uint2 i0 = *(const uint2*)(Ir0 + (size_t)(done+j  )*HD);
              uint2 i1 = *(const uint2*)(Ir0 + (size_t)(done+j+1)*HD);
              uint2 v0 = *(const uint2*)(Vprev + (size_t)s0*HD + l*4);
              uint2 v1 = *(const uint2*)(Vprev + (size_t)s1*HD + l*4);
              racc2(a, i0, v0); racc2(a, i1, v1);
            }
            if (j < m){
              int s0 = __shfl(idx, j);
              uint2 i0 = *(const uint2*)(Ir0 + (size_t)(done+j)*HD);
              uint2 v0 = *(const uint2*)(Vprev + (size_t)s0*HD + l*4);
              racc2(a, i0, v0);
            }
            done += m;
          }
        } else {
          int j = 0;
          for (; j+2 <= cnt; j+=2){
            uint2 i0 = *(const uint2*)(Ir0 + (size_t)j*HD);
            uint2 i1 = *(const uint2*)(Ir0 + (size_t)(j+1)*HD);
            racc1(a, i0); racc1(a, i1);
          }
          if (j < cnt) racc1(a, *(const uint2*)(Ir0 + (size_t)j*HD));
        }
      }
      ushort4 o; o.x=f2b(a[0]); o.y=f2b(a[1]); o.z=f2b(a[2]); o.w=f2b(a[3]);
      if (v < N && Sout) *(ushort4*)(Sout + (size_t)v*HD + l*4) = o;
      *(ushort4*)&A_lds[w*8+hh][l*4] = o;
    }
    __syncthreads();
    // ---- phase B: 4 row-tiles of 16, MFMA vs register B
    #pragma unroll
    for (int t4=0; t4<4; t4++){
      f32x4 acc0 = (f32x4){0.f,0.f,0.f,0.f};
      f32x4 acc1 = (f32x4){0.f,0.f,0.f,0.f};
      const u16* Ar = &A_lds[t4*16 + lr][0];
      #pragma unroll
      for (int ks=0; ks<8; ks++){
        bf16x8 af = *(const bf16x8*)(Ar + ks*32 + lq*8);
        acc0 = __builtin_amdgcn_mfma_f32_16x16x32_bf16(af, B0[ks], acc0, 0,0,0);
        acc1 = __builtin_amdgcn_mfma_f32_16x16x32_bf16(af, B1[ks], acc1, 0,0,0);
      }
      #pragma unroll
      for (int reg=0; reg<4; reg++){
        int gm = vb + t4*16 + lq*4 + reg;
        if (gm < N){
          if (mode == 1){
            float v0 = acc0[reg] + b2f(Radd[(size_t)gm*HD + c0]) + b0;
            float v1 = acc1[reg] + b2f(Radd[(size_t)gm*HD + c1]) + b1;
            hout[(size_t)gm*HD + c0] = v0 > 0.f ? v0 : 0.f;
            hout[(size_t)gm*HD + c1] = v1 > 0.f ? v1 : 0.f;
          } else {
            Vout[(size_t)gm*HD + c0] = f2b(acc0[reg]);
            Vout[(size_t)gm*HD + c1] = f2b(acc1[reg]);
          }
        }
      }
    }
    __syncthreads();
  }
}

// ---------------- backtracking correction (split, parallel — round-9 verified) ----------------
// corr1: per first-occurrence pair, deltaS[p] = m_true - m_naive; newA = m_true
__global__ __launch_bounds__(256) void k_corr1(
    const u16* __restrict__ I, const u16* __restrict__ Vprev,
    const int* __restrict__ esrc_p,
    const int2* __restrict__ pairs, const int* __restrict__ npairs_p,
    const float* __restrict__ Wh, const float* __restrict__ msgA,
    float* __restrict__ newA, float* __restrict__ deltaS)
{
  int np = *npairs_p; if (np > CORR_CAP) np = CORR_CAP;
  int t = threadIdx.x;
  __shared__ float cs[HD];
  for (int p = blockIdx.x; p < np; p += gridDim.x){
    int e = pairs[p].x;
    bool first = true;                      // block-uniform
    for (int q=0;q<p;q++) if (pairs[q].x == e){ first=false; break; }
    __syncthreads();
    if (first){
      float c = 0.f;
      for (int q=p;q<np;q++) if (pairs[q].x == e) c += msgA[(size_t)q*HD + t];
      cs[t] = c;
    }
    __syncthreads();
    if (first){
      float a0=0.f,a1=0.f,a2=0.f,a3=0.f;
      for (int k=0;k<HD;k+=4){
        a0 += cs[k]  *Wh[(size_t)k*HD+t];
        a1 += cs[k+1]*Wh[(size_t)(k+1)*HD+t];
        a2 += cs[k+2]*Wh[(size_t)(k+2)*HD+t];
        a3 += cs[k+3]*Wh[(size_t)(k+3)*HD+t];
      }
      float corr = (a0+a1)+(a2+a3);
      int u = esrc_p[e];
      float base = b2f(I[(size_t)e*HD + t]) + b2f(Vprev[(size_t)u*HD + t]);
      float mn = base > 0.f ? base : 0.f;
      float bt = base - corr;
      float mt = bt > 0.f ? bt : 0.f;
      deltaS[(size_t)p*HD + t] = mt - mn;
      for (int q=0;q<np;q++) if (pairs[q].y == e) newA[(size_t)q*HD + t] = mt;
    }
  }
}

// corrV (non-final): commit msgA=newA; per distinct affected dst, V[dv] += (sum deltaS)@Wh
__global__ __launch_bounds__(256) void k_corrV(
    const int2* __restrict__ pairs, const int* __restrict__ npairs_p,
    const int* __restrict__ edst_p, const float* __restrict__ deltaS,
    float* __restrict__ msgA, const float* __restrict__ newA,
    const float* __restrict__ Wh, u16* __restrict__ Vcur)
{
  int np = *npairs_p; if (np > CORR_CAP) np = CORR_CAP;
  int t = threadIdx.x;
  __shared__ float ds[HD];
  for (int p = blockIdx.x; p < np; p += gridDim.x)
    msgA[(size_t)p*HD + t] = newA[(size_t)p*HD + t];
  for (int p = blockIdx.x; p < np; p += gridDim.x){
    int dv = edst_p[pairs[p].x];
    bool firstdv = true;                    // block-uniform
    for (int q=0;q<p;q++) if (edst_p[pairs[q].x] == dv){ firstdv=false; break; }
    __syncthreads();
    if (firstdv){
      float d = 0.f;
      for (int q=p;q<np;q++){
        if (edst_p[pairs[q].x] != dv) continue;
        bool fe = true;
        for (int r=0;r<q;r++) if (pairs[r].x == pairs[q].x){ fe=false; break; }
        if (fe) d += deltaS[(size_t)q*HD + t];
      }
      ds[t] = d;
    }
    __syncthreads();
    if (firstdv){
      float a0=0.f,a1=0.f,a2=0.f,a3=0.f;
      for (int k=0;k<HD;k+=4){
        a0 += ds[k]  *Wh[(size_t)k*HD+t];
        a1 += ds[k+1]*Wh[(size_t)(k+1)*HD+t];
        a2 += ds[k+2]*Wh[(size_t)(k+2)*HD+t];
        a3 += ds[k+3]*Wh[(size_t)(k+3)*HD+t];
      }
      float dot = (a0+a1)+(a2+a3);
      u16* vp = Vcur + (size_t)dv*HD + t;
      *vp = f2b(b2f(*vp) + dot);
    }
  }
}

// corr2 (final only, single tiny block): apply deltaS to Scur; commit msgA
__global__ __launch_bounds__(256, 1) void k_corr2(
    const int2* __restrict__ pairs, const int* __restrict__ npairs_p,
    const int* __restrict__ edst_p, const float* __restrict__ deltaS,
    float* __restrict__ msgA, const float* __restrict__ newA,
    u16* __restrict__ Scur)
{
  int np = *npairs_p; if (np > CORR_CAP) np = CORR_CAP;
  int t = threadIdx.x;
  for (int p=0; p<np; p++){
    msgA[(size_t)p*HD + t] = newA[(size_t)p*HD + t];
    int e = pairs[p].x;
    bool first = true;
    for (int q=0;q<p;q++) if (pairs[q].x == e){ first=false; break; }
    if (first){
      int dv = edst_p[e];
      u16* sp = Scur + (size_t)dv*HD + t;
      *sp = f2b(b2f(*sp) + deltaS[(size_t)p*HD + t]);
    }
    __syncthreads();
  }
}

// corr3 (final): recompute h rows for distinct affected dst from corrected S
__global__ __launch_bounds__(256) void k_corr3(
    const int2* __restrict__ pairs, const int* __restrict__ npairs_p,
    const int* __restrict__ edst_p, const u16* __restrict__ Scur,
    const float* __restrict__ Wob, const u16* __restrict__ Radd,
    const float* __restrict__ bias, float* __restrict__ hout)
{
  int np = *npairs_p; if (np > CORR_CAP) np = CORR_CAP;
  int t = threadIdx.x;
  __shared__ float sa[HD];
  for (int p = blockIdx.x; p < np; p += gridDim.x){
    int dv = edst_p[pairs[p].x];
    bool first = true;                      // block-uniform
    for (int q=0;q<p;q++) if (edst_p[pairs[q].x] == dv){ first=false; break; }
    __syncthreads();
    if (first) sa[t] = b2f(Scur[(size_t)dv*HD + t]);
    __syncthreads();
    if (first){
      float a0=0.f,a1=0.f,a2=0.f,a3=0.f;
      for (int k=0;k<HD;k+=4){
        a0 += sa[k]  *Wob[(size_t)k*HD+t];
        a1 += sa[k+1]*Wob[(size_t)(k+1)*HD+t];
        a2 += sa[k+2]*Wob[(size_t)(k+2)*HD+t];
        a3 += sa[k+3]*Wob[(size_t)(k+3)*HD+t];
      }
      float acc = (a0+a1)+(a2+a3);
      float hv = acc + b2f(Radd[(size_t)dv*HD + t]) + bias[t];
      hout[(size_t)dv*HD + t] = hv > 0.f ? hv : 0.f;
    }
  }
}

// ---------------- graph mean (graph_ids sorted), fp32 in/out ----------------
__global__ void k_graph_mean(const float* __restrict__ h, const int* __restrict__ gid,
                             int N, int G, float* __restrict__ out){
  int g = (int)(((long long)blockIdx.x*blockDim.x + threadIdx.x)>>6);
  int l = threadIdx.x & 63;
  if (g >= G) return;
  int lo=0, hi=N;
  while (lo<hi){ int mid=(lo+hi)>>1; if (gid[mid] < g) lo=mid+1; else hi=mid; }
  int b = lo;
  hi = N;
  while (lo<hi){ int mid=(lo+hi)>>1; if (gid[mid] < g+1) lo=mid+1; else hi=mid; }
  int e2 = lo;
  float a0=0.f,a1=0.f,a2=0.f,a3=0.f;
  for (int v=b; v<e2; v++){
    float4 hv = *(const float4*)(h + (size_t)v*HD + l*4);
    a0 += hv.x; a1 += hv.y; a2 += hv.z; a3 += hv.w;
  }
  int cnt = e2 - b; if (cnt < 1) cnt = 1;
  float inv = 1.0f/(float)cnt;
  float4 o; o.x=a0*inv; o.y=a1*inv; o.z=a2*inv; o.w=a3*inv;
  *(float4*)(out + (size_t)g*HD + l*4) = o;
}

extern "C" void kernel_launch(void* const* d_in, const int* in_sizes, int n_in,
                              void* d_out, int out_size, void* d_ws, size_t ws_size,
                              hipStream_t stream){
  const float* x_nodes = (const float*)d_in[0];
  const float* x_edges = (const float*)d_in[1];
  const float* tree_m  = (const float*)d_in[2];
  const float* W_i     = (const float*)d_in[3];
  const float* W_h     = (const float*)d_in[4];
  const float* W_o     = (const float*)d_in[5];
  const float* b_o     = (const float*)d_in[6];
  const int* edge_src = (const int*)d_in[7];
  const int* edge_dst = (const int*)d_in[8];
  const int* tgt      = (const int*)d_in[11];
  const int* teid     = (const int*)d_in[12];
  const int* gid      = (const int*)d_in[13];

  const int N = in_sizes[0]/35;
  const int E = in_sizes[1]/5;
  const int K = in_sizes[11];
  const int G = out_size/HD;
  const int N2 = 2*N;

  // ---- workspace layout (~277 MB) ----
  char* wsb = (char*)d_ws;
  auto align256 = [](size_t x){ return (x + 255) & ~(size_t)255; };
  size_t oI      = 0;                                          // 102.4 MB
  size_t oSa     = oI      + align256((size_t)E*HD*2);         // 25.6 MB
  size_t oVa     = oSa     + align256((size_t)N*HD*2);         // 25.6 MB
  size_t oP      = oVa     + align256((size_t)N*HD*2);         // 25.6 MB (hbuf lo)
  size_t oVb     = oP      + align256((size_t)N*HD*2);         // 25.6 MB (hbuf hi)
  size_t oR      = oVb     + align256((size_t)N*HD*2);         // 25.6 MB
  size_t oAlpha  = oR      + align256((size_t)N*HD*2);         // 25.6 MB
  size_t oXnf    = oAlpha  + align256((size_t)N*HD*2);         // 6.4 MB
  size_t oXep    = oXnf    + align256((size_t)N*64*2);         // 4.0 MB
  size_t oBTP    = oXep    + align256((size_t)E*5*4);
  size_t oBTWh   = oBTP    + align256((size_t)2*16*512*2);
  size_t oBTRa   = oBTWh   + align256((size_t)8*16*512*2);
  size_t oBTWob  = oBTRa   + align256((size_t)2*16*512*2);
  size_t oDeg2   = oBTWob  + align256((size_t)8*16*512*2);     // 2N+1 ints ([2N]=npairs)
  size_t oStart2 = oDeg2   + align256((size_t)(N2+1)*4);       // 2N+1 ints
  size_t oCur2   = oStart2 + align256((size_t)(N2+1)*4);       // 2N ints
  size_t oBuk2   = oCur2   + align256((size_t)N2*4);           // K+E ints
  size_t oEsrcP  = oBuk2   + align256((size_t)(K+E)*4);
  size_t oEdstP  = oEsrcP  + align256((size_t)E*4);
  size_t oBsum   = oEdstP  + align256((size_t)E*4);
  size_t oPairs  = oBsum   + align256((size_t)1024*4);
  size_t oMsgA   = oPairs  + align256((size_t)CORR_CAP*8);     // 2 MB
  size_t oNewA   = oMsgA   + align256((size_t)CORR_CAP*HD*4);  // 2 MB
  size_t oDeltaS = oNewA   + align256((size_t)CORR_CAP*HD*4);  // 2 MB

  u16*   I       = (u16*)(wsb + oI);
  u16*   Sa      = (u16*)(wsb + oSa);
  u16*   Va      = (u16*)(wsb + oVa);
  u16*   P       = (u16*)(wsb + oP);
  u16*   Vb      = (u16*)(wsb + oVb);
  u16*   R       = (u16*)(wsb + oR);
  u16*   alpha16 = (u16*)(wsb + oAlpha);
  u16*   xnf     = (u16*)(wsb + oXnf);
  float* xep     = (float*)(wsb + oXep);
  u16*   BT_P    = (u16*)(wsb + oBTP);
  u16*   BT_Wh   = (u16*)(wsb + oBTWh);
  u16*   BT_Ra   = (u16*)(wsb + oBTRa);
  u16*   BT_Wob  = (u16*)(wsb + oBTWob);
  int*   deg2    = (int*)(wsb + oDeg2);
  int*   npairs  = deg2 + N2;                 // zeroed in k_prep_all
  int*   start2  = (int*)(wsb + oStart2);
  int*   cursor2 = (int*)(wsb + oCur2);
  int*   bucket2 = (int*)(wsb + oBuk2);
  int*   esrc_p  = (int*)(wsb + oEsrcP);
  int*   edst_p  = (int*)(wsb + oEdstP);
  int*   bsum    = (int*)(wsb + oBsum);
  int2*  pairs   = (int2*)(wsb + oPairs);
  float* msgA    = (float*)(wsb + oMsgA);
  float* newA    = (float*)(wsb + oNewA);
  float* deltaS  = (float*)(wsb + oDeltaS);
  // hbuf (N*HD fp32 = 51.2 MB) overlays P+Vb: P dead after build_I, Vb dead after call2
  float* hbuf    = (float*)(wsb + oP);

  const int egrid256 = (E+255)/256;
  const int kgrid256 = (K+255)/256;
  const int nb2      = (N2+255)/256;                    // 391 <= 1024
  const int zb       = (N2+1+255)/256;
  const int xnfb     = (int)(((size_t)N*64+255)/256);
  const int agrid    = (N+3)/4;
  const int ngrp     = (N+GRP-1)/GRP;

  // ---- fused prep: B tables + xnf + zero(deg2,npairs)
  k_prep_all<<<640+zb+xnfb, 256, 0, stream>>>(W_i, W_h, W_o, x_nodes,
                                              BT_P, BT_Wh, BT_Ra, BT_Wob,
                                              xnf, deg2, N, zb);
  // ---- concatenated histograms + single scan + fused fills
  k_hist2<<<kgrid256+egrid256, 256, 0, stream>>>(tgt, edge_dst, deg2, K, E, N, kgrid256);
  k_scan_p1<<<nb2, 256, 0, stream>>>(deg2, N2, bsum);
  k_scan_p2<<<1, 1024, 0, stream>>>(bsum, nb2, start2 + N2);   // start2[2N] = K+E
  k_scan_p3<<<nb2, 256, 0, stream>>>(deg2, bsum, N2, start2, cursor2);
  k_fill2<<<kgrid256+egrid256, 256, 0, stream>>>(tgt, teid, edge_dst, cursor2, bucket2,
                                                 K, E, N, kgrid256);
  k_perm_xep<<<egrid256, 256, 0, stream>>>(bucket2, K, edge_src, edge_dst, x_edges,
                                           esrc_p, edst_p, xep, E);
  k_alpha_pairs<<<agrid+egrid256, 256, 0, stream>>>(tree_m, start2, bucket2, alpha16,
                                                    esrc_p, edst_p, npairs, pairs,
                                                    N, E, K, agrid);
  // ---- P = xn@Wi_a, R = xn@Wo_a
  k_pr2<<<512, 512, 0, stream>>>(xnf, BT_P, BT_Ra, P, R, N);
  // ---- I = P[src] + xe@Wi_b (pre-relu); msgA = msg_0 of partner edges
  k_build_I<<<2048, 256, 0, stream>>>(P, xep, esrc_p, W_i, I, E);
  k_msgA0<<<64, 256, 0, stream>>>(I, pairs, npairs, msgA);

  const float* Wob = W_o + 35*HD;
  const int* start_d = start2 + N;   // absolute, bias K

  // ---- call0: S_0 = alpha + sum relu(I); V_0 = S_0@Wh  (exact, no correction)
  k_bp<<<ngrp, 512, 0, stream>>>(I, (const u16*)0, alpha16, start_d, K, esrc_p, BT_Wh,
                                 (const u16*)0, (const float*)0,
                                 (u16*)0, Va, (float*)0, N, 0);
  // ---- call1: V_0 -> V_1 (Vb); corr1 + additive V patch
  k_bp<<<ngrp, 512, 0, stream>>>(I, Va, alpha16, start_d, K, esrc_p, BT_Wh,
                                 (const u16*)0, (const float*)0,
                                 (u16*)0, Vb, (float*)0, N, 0);
  k_corr1<<<64, 256, 0, stream>>>(I, Va, esrc_p, pairs, npairs, W_h, msgA, newA, deltaS);
  k_corrV<<<64, 256, 0, stream>>>(pairs, npairs, edst_p, deltaS, msgA, newA, W_h, Vb);
  // ---- call2: V_1 -> V_2 (Va); corr1 + additive V patch
  k_bp<<<ngrp, 512, 0, stream>>>(I, Vb, alpha16, start_d, K, esrc_p, BT_Wh,
                                 (const u16*)0, (const float*)0,
                                 (u16*)0, Va, (float*)0, N, 0);
  k_corr1<<<64, 256, 0, stream>>>(I, Vb, esrc_p, pairs, npairs, W_h, msgA, newA, deltaS);
  k_corrV<<<64, 256, 0, stream>>>(pairs, npairs, edst_p, deltaS, msgA, newA, W_h, Va);
  // ---- call3 (final): h = relu(R + S_3@Wo_b + b); exact S-based correction
  k_bp<<<ngrp, 512, 0, stream>>>(I, Va, alpha16, start_d, K, esrc_p, BT_Wob,
                                 R, b_o, Sa, (u16*)0, hbuf, N, 1);
  k_corr1<<<64, 256, 0, stream>>>(I, Va, esrc_p, pairs, npairs, W_h, msgA, newA, deltaS);
  k_corr2<<<1, 256, 0, stream>>>(pairs, npairs, edst_p, deltaS, msgA, newA, Sa);
  k_corr3<<<64, 256, 0, stream>>>(pairs, npairs, edst_p, Sa, Wob, R, b_o, hbuf);

  k_graph_mean<<<(G+3)/4, 256, 0, stream>>>(hbuf, gid, N, G, (float*)d_out);
}